// Round 17
// baseline (659.226 us; speedup 1.0000x reference)
//
#include <hip/hip_runtime.h>
#include <stdint.h>

#define NSITES 256
#define NHID   64
#define BATCH  8192

typedef float v4f __attribute__((ext_vector_type(4)));
typedef short v8s __attribute__((ext_vector_type(8)));

// ---------------- threefry2x32 (exact JAX semantics) ----------------
__device__ __forceinline__ uint32_t rotl32(uint32_t v, int d) {
  return (v << d) | (v >> (32 - d));
}

__device__ __forceinline__ void tf2x32(uint32_t k0, uint32_t k1,
                                       uint32_t x0, uint32_t x1,
                                       uint32_t& o0, uint32_t& o1) {
  uint32_t ks2 = k0 ^ k1 ^ 0x1BD11BDAu;
  x0 += k0; x1 += k1;
#define TFR4(a,b,c,d) \
  x0 += x1; x1 = rotl32(x1,a); x1 ^= x0; \
  x0 += x1; x1 = rotl32(x1,b); x1 ^= x0; \
  x0 += x1; x1 = rotl32(x1,c); x1 ^= x0; \
  x0 += x1; x1 = rotl32(x1,d); x1 ^= x0;
  TFR4(13,15,26,6)   x0 += k1;  x1 += ks2 + 1u;
  TFR4(17,29,16,24)  x0 += ks2; x1 += k0  + 2u;
  TFR4(13,15,26,6)   x0 += k0;  x1 += k1  + 3u;
  TFR4(17,29,16,24)  x0 += k1;  x1 += ks2 + 4u;
  TFR4(13,15,26,6)   x0 += ks2; x1 += k0  + 5u;
#undef TFR4
  o0 = x0; o1 = x1;
}

__device__ __forceinline__ float gumb_from_bits(uint32_t bits) {
  float f = __uint_as_float((bits >> 9) | 0x3f800000u) - 1.0f;
  float u = (f == 0.0f) ? 1.17549435e-38f : f;
  return -logf(-logf(u));
}

__device__ __forceinline__ uint32_t rbits32(uint32_t k0, uint32_t k1, uint32_t e) {
  uint32_t a, b;
  tf2x32(k0, k1, 0u, e, a, b);
  return a ^ b;
}

// ------ [WhT ; Wd-replicated ; zeros] (208 x 64) -> 3-term bf16 split ------
__global__ void split_awt(const float* __restrict__ Wh, const float* __restrict__ Wd,
                          ushort* __restrict__ w0, ushort* __restrict__ w1,
                          ushort* __restrict__ w2) {
  int idx = blockIdx.x * 256 + threadIdx.x;   // 0..13311 = col*64 + j
  if (idx >= 208 * 64) return;
  int col = idx >> 6;
  int j   = idx & 63;
  float w;
  if (col < 192) {
    w = Wh[j * 192 + col];
  } else {
    const int which = (col - 192) & 3;
    w = (which == 0) ? Wd[j * 2] : (which == 1) ? Wd[j * 2 + 1] : 0.0f;
  }
  uint32_t u0 = __float_as_uint(w) & 0xffff0000u;
  float f0 = __uint_as_float(u0);
  float r1 = w - f0;
  uint32_t u1 = __float_as_uint(r1) & 0xffff0000u;
  float f1 = __uint_as_float(u1);
  float r2 = r1 - f1;
  uint32_t u2 = __float_as_uint(r2) & 0xffff0000u;
  w0[idx] = (ushort)(u0 >> 16);
  w1[idx] = (ushort)(u1 >> 16);
  w2[idx] = (ushort)(u2 >> 16);
}

// XLA's logistic_expander form: 0.5 + 0.5*tanh(0.5*x)
__device__ __forceinline__ float sigmoid_xla(float x) {
  return 0.5f + 0.5f * tanhf(0.5f * x);
}

// 128-step gumbel window: thread (tid&127) = step, (tid>>7) picks sample half
__device__ __forceinline__ void gen_gl(float2* gl, int base, int tid, int phase) {
  const int st = phase * 128 + (tid & 127);
  const int kb = (tid >> 7) * 16;
  uint32_t kt0, kt1;
  tf2x32(0u, 1234u, 0u, (uint32_t)st, kt0, kt1);
  for (int k = 0; k < 16; ++k) {
    const int bidx = base + kb + k;
    const float g0 = gumb_from_bits(rbits32(kt0, kt1, (uint32_t)(2 * bidx)));
    const float g1 = gumb_from_bits(rbits32(kt0, kt1, (uint32_t)(2 * bidx + 1)));
    gl[(tid & 127) * 32 + kb + k] = make_float2(g0, g1);
  }
}

#define MF(A_, B_, C_) __builtin_amdgcn_mfma_f32_16x16x32_bf16((A_), (B_), (C_), 0, 0, 0)
#define F4(v_, r_) (((const float*)&(v_))[r_])

// ============ MFMA kernel v11: dual sample-set per wave ===================
// 32 samples/block (sets X,Y of 16), grid 256 = 1 block/CU, 2 waves/SIMD.
// Each wave runs TWO independent per-step pipelines sharing the same
// A-fragment registers: while X's serial chains (logits MFMA chain, tanh)
// sit in latency, Y's independent work issues.  Per-sample FP ops are
// bit-identical to R16 -> absmax 0.0 by construction.  Gumbels live in a
// 128-step LDS window regenerated once at t=128.
__global__ __launch_bounds__(256, 2)
void rnn_mfma11(const float* __restrict__ Wi, const float* __restrict__ bb,
                const float* __restrict__ bd,
                const ushort* __restrict__ w0p, const ushort* __restrict__ w1p,
                const ushort* __restrict__ w2p,
                float* __restrict__ out_s, float* __restrict__ out_lp) {
  __shared__ __align__(16) ushort bspX[2][3072];    // set X h splits
  __shared__ __align__(16) ushort bspY[2][3072];    // set Y h splits
  __shared__ __align__(16) float2 gl[128 * 32];     // gumbel window, 32 KiB
  __shared__ __align__(16) float c0zr[128];
  __shared__ __align__(16) float bh0a[64], bh1a[64];
  __shared__ __align__(16) float cw0[192], cw1[192];

  const int tid = threadIdx.x;
  const int l = tid & 63, s = l & 15, hi = l >> 4;
  const int w = tid >> 6;
  const int base = blockIdx.x * 32;

  if (tid < 64) {
    c0zr[tid] = bb[tid] + bb[192 + tid];
    c0zr[tid + 64] = bb[tid + 64] + bb[256 + tid];
    bh0a[tid] = bb[128 + tid];
    bh1a[tid] = bb[320 + tid];
    cw0[tid] = Wi[tid]; cw0[tid + 64] = Wi[tid + 64]; cw0[tid + 128] = Wi[tid + 128];
    cw1[tid] = Wi[192 + tid]; cw1[tid + 64] = Wi[256 + tid]; cw1[tid + 128] = Wi[320 + tid];
  }
  for (int k = tid; k < 1536; k += 256) {
    ((uint*)bspX[0])[k] = 0u;   // h(-1) = 0 splits
    ((uint*)bspY[0])[k] = 0u;
  }
  gen_gl(gl, base, tid, 0);     // gumbels for steps 0..127
  __syncthreads();

  // ---- A fragments: unit tiles {w,4+w,8+w} + logits tile 12, 3 splits ----
  v8s A0[3][2], A1[3][2], A2[3][2];
#pragma unroll
  for (int i3 = 0; i3 < 3; ++i3) {
    const int tile = w + 4 * i3;
#pragma unroll
    for (int kc = 0; kc < 2; ++kc) {
      const int off = (16 * tile + s) * 64 + 32 * kc + 8 * hi;
      A0[i3][kc] = *reinterpret_cast<const v8s*>(w0p + off);
      A1[i3][kc] = *reinterpret_cast<const v8s*>(w1p + off);
      A2[i3][kc] = *reinterpret_cast<const v8s*>(w2p + off);
    }
  }
  v8s L0[2], L1[2], L2[2];
#pragma unroll
  for (int kc = 0; kc < 2; ++kc) {
    const int off = (192 + s) * 64 + 32 * kc + 8 * hi;   // tile 12
    L0[kc] = *reinterpret_cast<const v8s*>(w0p + off);
    L1[kc] = *reinterpret_cast<const v8s*>(w1p + off);
    L2[kc] = *reinterpret_cast<const v8s*>(w2p + off);
  }

  const float bd0 = bd[0], bd1 = bd[1];
  const int u0i = 16 * w + 4 * hi;        // this wave's gate-unit group
  const float4 czv  = *reinterpret_cast<const float4*>(&c0zr[u0i]);
  const float4 crv  = *reinterpret_cast<const float4*>(&c0zr[64 + u0i]);
  const float4 bh0v = *reinterpret_cast<const float4*>(&bh0a[u0i]);
  const float4 bh1v = *reinterpret_cast<const float4*>(&bh1a[u0i]);
  const float4 wz0  = *reinterpret_cast<const float4*>(&cw0[u0i]);
  const float4 wz1  = *reinterpret_cast<const float4*>(&cw1[u0i]);
  const float4 wr0  = *reinterpret_cast<const float4*>(&cw0[64 + u0i]);
  const float4 wr1  = *reinterpret_cast<const float4*>(&cw1[64 + u0i]);
  const float4 wh0  = *reinterpret_cast<const float4*>(&cw0[128 + u0i]);
  const float4 wh1  = *reinterpret_cast<const float4*>(&cw1[128 + u0i]);

  const int kcw = w >> 1;
  const int hgw = (2 * w + (hi >> 1)) & 3;
  const int i0  = (hi & 1) * 4;

  float hregX[4] = {0.0f, 0.0f, 0.0f, 0.0f};
  float hregY[4] = {0.0f, 0.0f, 0.0f, 0.0f};
  float lpX = 0.0f, lpY = 0.0f;
  int p = 0;

  for (int t = 0; t <= NSITES; ++t) {
    // ---- gumbels (128-step window; slot = (t-1)&127) ----
    float2 gcX = make_float2(0.0f, 0.0f), gcY = make_float2(0.0f, 0.0f);
    if (t > 0) {
      const int gsl = ((t - 1) & 127) * 32;
      gcX = gl[gsl + s];
      gcY = gl[gsl + 16 + s];
    }
    if (t == 128) {              // all reads of window-0 done (gc above)
      __syncthreads();
      gen_gl(gl, base, tid, 1);  // steps 128..255; visible after loop barrier
    }

    // ================= set X =================
    const ushort* rbX = bspX[p] + hi * 128 + s * 8;
    v8s B0X[2], B1X[2], B2X[2];
#pragma unroll
    for (int kc = 0; kc < 2; ++kc) {
      B0X[kc] = *reinterpret_cast<const v8s*>(rbX + kc * 512);
      B1X[kc] = *reinterpret_cast<const v8s*>(rbX + 1024 + kc * 512);
      B2X[kc] = *reinterpret_cast<const v8s*>(rbX + 2048 + kc * 512);
    }
    v4f alX = {0.0f, 0.0f, 0.0f, 0.0f};
#pragma unroll
    for (int kc = 0; kc < 2; ++kc) alX = MF(L1[kc], B1X[kc], alX);
#pragma unroll
    for (int kc = 0; kc < 2; ++kc) alX = MF(L2[kc], B0X[kc], alX);
#pragma unroll
    for (int kc = 0; kc < 2; ++kc) alX = MF(L0[kc], B2X[kc], alX);
#pragma unroll
    for (int kc = 0; kc < 2; ++kc) alX = MF(L1[kc], B0X[kc], alX);
#pragma unroll
    for (int kc = 0; kc < 2; ++kc) alX = MF(L0[kc], B1X[kc], alX);
#pragma unroll
    for (int kc = 0; kc < 2; ++kc) alX = MF(L0[kc], B0X[kc], alX);

    v4f accX[3];
    if (t < NSITES) {
#pragma unroll
      for (int i3 = 0; i3 < 3; ++i3) {
        v4f a = {0.0f, 0.0f, 0.0f, 0.0f};
#pragma unroll
        for (int kc = 0; kc < 2; ++kc) a = MF(A2[i3][kc], B0X[kc], a);
#pragma unroll
        for (int kc = 0; kc < 2; ++kc) a = MF(A0[i3][kc], B2X[kc], a);
#pragma unroll
        for (int kc = 0; kc < 2; ++kc) a = MF(A1[i3][kc], B1X[kc], a);
#pragma unroll
        for (int kc = 0; kc < 2; ++kc) a = MF(A1[i3][kc], B0X[kc], a);
#pragma unroll
        for (int kc = 0; kc < 2; ++kc) a = MF(A0[i3][kc], B1X[kc], a);
#pragma unroll
        for (int kc = 0; kc < 2; ++kc) a = MF(A0[i3][kc], B0X[kc], a);
        accX[i3] = a;
      }
    }

    // ================= set Y =================
    const ushort* rbY = bspY[p] + hi * 128 + s * 8;
    v8s B0Y[2], B1Y[2], B2Y[2];
#pragma unroll
    for (int kc = 0; kc < 2; ++kc) {
      B0Y[kc] = *reinterpret_cast<const v8s*>(rbY + kc * 512);
      B1Y[kc] = *reinterpret_cast<const v8s*>(rbY + 1024 + kc * 512);
      B2Y[kc] = *reinterpret_cast<const v8s*>(rbY + 2048 + kc * 512);
    }
    v4f alY = {0.0f, 0.0f, 0.0f, 0.0f};
#pragma unroll
    for (int kc = 0; kc < 2; ++kc) alY = MF(L1[kc], B1Y[kc], alY);
#pragma unroll
    for (int kc = 0; kc < 2; ++kc) alY = MF(L2[kc], B0Y[kc], alY);
#pragma unroll
    for (int kc = 0; kc < 2; ++kc) alY = MF(L0[kc], B2Y[kc], alY);
#pragma unroll
    for (int kc = 0; kc < 2; ++kc) alY = MF(L1[kc], B0Y[kc], alY);
#pragma unroll
    for (int kc = 0; kc < 2; ++kc) alY = MF(L0[kc], B1Y[kc], alY);
#pragma unroll
    for (int kc = 0; kc < 2; ++kc) alY = MF(L0[kc], B0Y[kc], alY);

    v4f accY[3];
    if (t < NSITES) {
#pragma unroll
      for (int i3 = 0; i3 < 3; ++i3) {
        v4f a = {0.0f, 0.0f, 0.0f, 0.0f};
#pragma unroll
        for (int kc = 0; kc < 2; ++kc) a = MF(A2[i3][kc], B0Y[kc], a);
#pragma unroll
        for (int kc = 0; kc < 2; ++kc) a = MF(A0[i3][kc], B2Y[kc], a);
#pragma unroll
        for (int kc = 0; kc < 2; ++kc) a = MF(A1[i3][kc], B1Y[kc], a);
#pragma unroll
        for (int kc = 0; kc < 2; ++kc) a = MF(A1[i3][kc], B0Y[kc], a);
#pragma unroll
        for (int kc = 0; kc < 2; ++kc) a = MF(A0[i3][kc], B1Y[kc], a);
#pragma unroll
        for (int kc = 0; kc < 2; ++kc) a = MF(A0[i3][kc], B0Y[kc], a);
        accY[i3] = a;
      }
    }

    // ---- early decision compares (no exp/log on the gates' path) ----
    int scdX = 0, scdY = 0;
    float l0X = 0.0f, l1X = 0.0f, l0Y = 0.0f, l1Y = 0.0f;
    if (t > 0) {
      l0X = alX[0] + bd0; l1X = alX[1] + bd1;
      scdX = ((l1X + gcX.y) > (l0X + gcX.x)) ? 1 : 0;
      l0Y = alY[0] + bd0; l1Y = alY[1] + bd1;
      scdY = ((l1Y + gcY.y) > (l0Y + gcY.x)) ? 1 : 0;
    }

    if (t < NSITES) {
      // ---- gates X ----
      {
        float selz[4], selr[4], selh[4];
        if (t == 0) {
#pragma unroll
          for (int r = 0; r < 4; ++r) { selz[r] = 0.0f; selr[r] = 0.0f; selh[r] = 0.0f; }
        } else {
#pragma unroll
          for (int r = 0; r < 4; ++r) {
            selz[r] = scdX ? F4(wz1, r) : F4(wz0, r);
            selr[r] = scdX ? F4(wr1, r) : F4(wr0, r);
            selh[r] = scdX ? F4(wh1, r) : F4(wh0, r);
          }
        }
        uint sp0[4], sp1[4], sp2[4];
#pragma unroll
        for (int r = 0; r < 4; ++r) {
          const float zin = accX[0][r] + F4(czv, r) + selz[r];
          const float rin = accX[1][r] + F4(crv, r) + selr[r];
          const float rhv = accX[2][r] + F4(bh1v, r);
          const float xhv = F4(bh0v, r) + selh[r];
          const float zg = sigmoid_xla(zin);
          const float rg = sigmoid_xla(rin);
          const float hg = tanhf(xhv + rg * rhv);
          const float hn = zg * hregX[r] + (1.0f - zg) * hg;
          hregX[r] = hn;
          const uint u0 = __float_as_uint(hn) & 0xffff0000u;
          const float f0 = __uint_as_float(u0);
          const float r1f = hn - f0;
          const uint u1 = __float_as_uint(r1f) & 0xffff0000u;
          const float f1 = __uint_as_float(u1);
          const float r2f = r1f - f1;
          const uint u2 = __float_as_uint(r2f) & 0xffff0000u;
          sp0[r] = u0 >> 16; sp1[r] = u1 >> 16; sp2[r] = u2 >> 16;
        }
        ushort* wb = bspX[p ^ 1] + kcw * 512 + hgw * 128 + s * 8 + i0;
        uint2 q;
        q.x = sp0[0] | (sp0[1] << 16); q.y = sp0[2] | (sp0[3] << 16);
        *reinterpret_cast<uint2*>(wb) = q;
        q.x = sp1[0] | (sp1[1] << 16); q.y = sp1[2] | (sp1[3] << 16);
        *reinterpret_cast<uint2*>(wb + 1024) = q;
        q.x = sp2[0] | (sp2[1] << 16); q.y = sp2[2] | (sp2[3] << 16);
        *reinterpret_cast<uint2*>(wb + 2048) = q;
      }
      // ---- gates Y ----
      {
        float selz[4], selr[4], selh[4];
        if (t == 0) {
#pragma unroll
          for (int r = 0; r < 4; ++r) { selz[r] = 0.0f; selr[r] = 0.0f; selh[r] = 0.0f; }
        } else {
#pragma unroll
          for (int r = 0; r < 4; ++r) {
            selz[r] = scdY ? F4(wz1, r) : F4(wz0, r);
            selr[r] = scdY ? F4(wr1, r) : F4(wr0, r);
            selh[r] = scdY ? F4(wh1, r) : F4(wh0, r);
          }
        }
        uint sp0[4], sp1[4], sp2[4];
#pragma unroll
        for (int r = 0; r < 4; ++r) {
          const float zin = accY[0][r] + F4(czv, r) + selz[r];
          const float rin = accY[1][r] + F4(crv, r) + selr[r];
          const float rhv = accY[2][r] + F4(bh1v, r);
          const float xhv = F4(bh0v, r) + selh[r];
          const float zg = sigmoid_xla(zin);
          const float rg = sigmoid_xla(rin);
          const float hg = tanhf(xhv + rg * rhv);
          const float hn = zg * hregY[r] + (1.0f - zg) * hg;
          hregY[r] = hn;
          const uint u0 = __float_as_uint(hn) & 0xffff0000u;
          const float f0 = __uint_as_float(u0);
          const float r1f = hn - f0;
          const uint u1 = __float_as_uint(r1f) & 0xffff0000u;
          const float f1 = __uint_as_float(u1);
          const float r2f = r1f - f1;
          const uint u2 = __float_as_uint(r2f) & 0xffff0000u;
          sp0[r] = u0 >> 16; sp1[r] = u1 >> 16; sp2[r] = u2 >> 16;
        }
        ushort* wb = bspY[p ^ 1] + kcw * 512 + hgw * 128 + s * 8 + i0;
        uint2 q;
        q.x = sp0[0] | (sp0[1] << 16); q.y = sp0[2] | (sp0[3] << 16);
        *reinterpret_cast<uint2*>(wb) = q;
        q.x = sp1[0] | (sp1[1] << 16); q.y = sp1[2] | (sp1[3] << 16);
        *reinterpret_cast<uint2*>(wb + 1024) = q;
        q.x = sp2[0] | (sp2[1] << 16); q.y = sp2[2] | (sp2[3] << 16);
        *reinterpret_cast<uint2*>(wb + 2048) = q;
      }
    }

    // ---- deferred scoring: exp/log overlaps barrier + next step's reads --
    if (t > 0) {
      const float mmX = fmaxf(l0X, l1X);
      const float sh0X = l0X - mmX, sh1X = l1X - mmX;
      const float lseX = logf(expf(sh0X) + expf(sh1X));
      lpX += (scdX ? sh1X : sh0X) - lseX;
      const float mmY = fmaxf(l0Y, l1Y);
      const float sh0Y = l0Y - mmY, sh1Y = l1Y - mmY;
      const float lseY = logf(expf(sh0Y) + expf(sh1Y));
      lpY += (scdY ? sh1Y : sh0Y) - lseY;
      if (tid < 16) {
        out_s[(size_t)(base + s) * NSITES + (t - 1)] = (float)scdX;
        out_s[(size_t)(base + 16 + s) * NSITES + (t - 1)] = (float)scdY;
      }
    }

    __syncthreads();   // h(t) splits + (at t==128) new gumbels visible
    p ^= 1;
  }

  if (tid < 16) {
    out_lp[base + s] = 0.5f * lpX;
    out_lp[base + 16 + s] = 0.5f * lpY;
  }
}

// ---------------- fallback (ws too small): proven bit-exact path ----------
__global__ __launch_bounds__(64)
void rnn_plain(const float* __restrict__ Wi, const float* __restrict__ Wh,
               const float* __restrict__ bb, const float* __restrict__ Wd,
               const float* __restrict__ bd,
               float* __restrict__ out_s, float* __restrict__ out_lp) {
  const int lane = threadIdx.x;
  const int b = blockIdx.x;

  float wz[NHID], wr[NHID], wh[NHID];
#pragma unroll
  for (int j = 0; j < NHID; ++j) {
    wz[j] = Wh[j * 192 + lane];
    wr[j] = Wh[j * 192 + 64 + lane];
    wh[j] = Wh[j * 192 + 128 + lane];
  }
  const float b1z = bb[192 + lane];
  const float b1r = bb[192 + 64 + lane];
  const float b1h = bb[192 + 128 + lane];
  const float m0z = bb[lane], m0r = bb[64 + lane], m0h = bb[128 + lane];
  const float m1z = Wi[lane] + m0z, m1r = Wi[64 + lane] + m0r, m1h = Wi[128 + lane] + m0h;
  const float m2z = Wi[192 + lane] + m0z, m2r = Wi[192 + 64 + lane] + m0r,
              m2h = Wi[192 + 128 + lane] + m0h;
  const float wd0 = Wd[lane * 2 + 0], wd1 = Wd[lane * 2 + 1];
  const float bd0 = bd[0], bd1 = bd[1];

  float h = 0.0f, lpsum = 0.0f;
  float xz = m0z, xr = m0r, xh = m0h;

  for (int t = 0; t < NSITES; ++t) {
    uint32_t kt0, kt1;
    tf2x32(0u, 1234u, 0u, (uint32_t)t, kt0, kt1);
    const float g0 = gumb_from_bits(rbits32(kt0, kt1, (uint32_t)(2 * b)));
    const float g1 = gumb_from_bits(rbits32(kt0, kt1, (uint32_t)(2 * b + 1)));

    float az = 0.0f, ar = 0.0f, ah = 0.0f;
#pragma unroll
    for (int j = 0; j < NHID; ++j) {
      const float hj = __int_as_float(__builtin_amdgcn_readlane(__float_as_int(h), j));
      az = fmaf(hj, wz[j], az);
      ar = fmaf(hj, wr[j], ar);
      ah = fmaf(hj, wh[j], ah);
    }
    const float rz = az + b1z, rr = ar + b1r, rh = ah + b1h;
    const float zg = sigmoid_xla(xz + rz);
    const float rg = sigmoid_xla(xr + rr);
    const float hg = tanhf(xh + rg * rh);
    h = zg * h + (1.0f - zg) * hg;

    float p0 = h * wd0, p1 = h * wd1;
#pragma unroll
    for (int off = 32; off > 0; off >>= 1) {
      p0 += __shfl_xor(p0, off, 64);
      p1 += __shfl_xor(p1, off, 64);
    }
    const float l0 = p0 + bd0, l1 = p1 + bd1;
    const float mmax = fmaxf(l0, l1);
    const float sh0 = l0 - mmax, sh1 = l1 - mmax;
    const float lse = logf(expf(sh0) + expf(sh1));
    const int si = ((l1 + g1) > (l0 + g0)) ? 1 : 0;
    lpsum += (si ? sh1 : sh0) - lse;
    if (lane == 0) out_s[(size_t)b * NSITES + t] = (float)si;
    xz = si ? m2z : m1z;
    xr = si ? m2r : m1r;
    xh = si ? m2h : m1h;
  }

  if (lane == 0) out_lp[b] = 0.5f * lpsum;
}

extern "C" void kernel_launch(void* const* d_in, const int* in_sizes, int n_in,
                              void* d_out, int out_size, void* d_ws, size_t ws_size,
                              hipStream_t stream) {
  const float* Wi = (const float*)d_in[1];
  const float* Wh = (const float*)d_in[2];
  const float* bb = (const float*)d_in[3];
  const float* Wd = (const float*)d_in[4];
  const float* bd = (const float*)d_in[5];

  float* out    = (float*)d_out;
  float* out_s  = out;                           // [8192][256]
  float* out_lp = out + (size_t)BATCH * NSITES;  // [8192]

  const size_t wb = (size_t)208 * 64 * sizeof(ushort);   // 26 KiB per split

  if (ws_size >= 3 * wb) {
    ushort* w0 = (ushort*)d_ws;
    ushort* w1 = w0 + 208 * 64;
    ushort* w2 = w1 + 208 * 64;
    split_awt<<<(208 * 64 + 255) / 256, 256, 0, stream>>>(Wh, Wd, w0, w1, w2);
    rnn_mfma11<<<BATCH / 32, 256, 0, stream>>>(Wi, bb, bd, w0, w1, w2, out_s, out_lp);
  } else {
    rnn_plain<<<BATCH, 64, 0, stream>>>(Wi, Wh, bb, Wd, bd, out_s, out_lp);
  }
}

// Round 18
// 393.990 us; speedup vs baseline: 1.6732x; 1.6732x over previous
//
#include <hip/hip_runtime.h>
#include <stdint.h>

#define NSITES 256
#define NHID   64
#define BATCH  8192

typedef float v4f __attribute__((ext_vector_type(4)));
typedef short v8s __attribute__((ext_vector_type(8)));

// ---------------- threefry2x32 (exact JAX semantics) ----------------
__device__ __forceinline__ uint32_t rotl32(uint32_t v, int d) {
  return (v << d) | (v >> (32 - d));
}

__device__ __forceinline__ void tf2x32(uint32_t k0, uint32_t k1,
                                       uint32_t x0, uint32_t x1,
                                       uint32_t& o0, uint32_t& o1) {
  uint32_t ks2 = k0 ^ k1 ^ 0x1BD11BDAu;
  x0 += k0; x1 += k1;
#define TFR4(a,b,c,d) \
  x0 += x1; x1 = rotl32(x1,a); x1 ^= x0; \
  x0 += x1; x1 = rotl32(x1,b); x1 ^= x0; \
  x0 += x1; x1 = rotl32(x1,c); x1 ^= x0; \
  x0 += x1; x1 = rotl32(x1,d); x1 ^= x0;
  TFR4(13,15,26,6)   x0 += k1;  x1 += ks2 + 1u;
  TFR4(17,29,16,24)  x0 += ks2; x1 += k0  + 2u;
  TFR4(13,15,26,6)   x0 += k0;  x1 += k1  + 3u;
  TFR4(17,29,16,24)  x0 += k1;  x1 += ks2 + 4u;
  TFR4(13,15,26,6)   x0 += ks2; x1 += k0  + 5u;
#undef TFR4
  o0 = x0; o1 = x1;
}

__device__ __forceinline__ float gumb_from_bits(uint32_t bits) {
  float f = __uint_as_float((bits >> 9) | 0x3f800000u) - 1.0f;
  float u = (f == 0.0f) ? 1.17549435e-38f : f;
  return -logf(-logf(u));
}

__device__ __forceinline__ uint32_t rbits32(uint32_t k0, uint32_t k1, uint32_t e) {
  uint32_t a, b;
  tf2x32(k0, k1, 0u, e, a, b);
  return a ^ b;
}

// ------ [WhT ; Wd-replicated ; zeros] (208 x 64) -> 3-term bf16 split ------
// rows 0-191: WhT[gate*64+unit][j].  rows 192-207 (logits tile): row
// 192+4k+0 = Wd col0, 192+4k+1 = Wd col1, else 0 -> every lane's D regs
// 0/1 hold l0/l1 (bitwise-identical MFMA rows) -> all-lane local decision.
__global__ void split_awt(const float* __restrict__ Wh, const float* __restrict__ Wd,
                          ushort* __restrict__ w0, ushort* __restrict__ w1,
                          ushort* __restrict__ w2) {
  int idx = blockIdx.x * 256 + threadIdx.x;   // 0..13311 = col*64 + j
  if (idx >= 208 * 64) return;
  int col = idx >> 6;
  int j   = idx & 63;
  float w;
  if (col < 192) {
    w = Wh[j * 192 + col];
  } else {
    const int which = (col - 192) & 3;
    w = (which == 0) ? Wd[j * 2] : (which == 1) ? Wd[j * 2 + 1] : 0.0f;
  }
  uint32_t u0 = __float_as_uint(w) & 0xffff0000u;
  float f0 = __uint_as_float(u0);
  float r1 = w - f0;
  uint32_t u1 = __float_as_uint(r1) & 0xffff0000u;
  float f1 = __uint_as_float(u1);
  float r2 = r1 - f1;
  uint32_t u2 = __float_as_uint(r2) & 0xffff0000u;
  w0[idx] = (ushort)(u0 >> 16);
  w1[idx] = (ushort)(u1 >> 16);
  w2[idx] = (ushort)(u2 >> 16);
}

// XLA's logistic_expander form: 0.5 + 0.5*tanh(0.5*x)
__device__ __forceinline__ float sigmoid_xla(float x) {
  return 0.5f + 0.5f * tanhf(0.5f * x);
}

#define MF(A_, B_, C_) __builtin_amdgcn_mfma_f32_16x16x32_bf16((A_), (B_), (C_), 0, 0, 0)
#define F4(v_, r_) (((const float*)&(v_))[r_])

// ============ MFMA kernel v10 (best measured: R16) =======================
// 16 samples/block, 4 waves (512 blocks = 2 blocks/CU = 2 waves/SIMD).
// Wave w owns unit-tiles {w,4+w,8+w}; logits as a 13th Wd-replicated MFMA
// tile -> all-lane local decision, no shfl; gumbels generated in-block;
// early decision compare + deferred exp/log scoring; one barrier/step.
__global__ __launch_bounds__(256, 2)
void rnn_mfma10(const float* __restrict__ Wi, const float* __restrict__ bb,
                const float* __restrict__ bd,
                const ushort* __restrict__ w0p, const ushort* __restrict__ w1p,
                const ushort* __restrict__ w2p,
                float* __restrict__ out_s, float* __restrict__ out_lp) {
  __shared__ __align__(16) ushort bsp[2][3072];     // h splits, B-frag layout
  __shared__ __align__(16) float2 gl[NSITES * 16];  // gumbels [t][s], 32 KiB
  __shared__ __align__(16) float c0zr[128];
  __shared__ __align__(16) float bh0a[64], bh1a[64];
  __shared__ __align__(16) float cw0[192], cw1[192];

  const int tid = threadIdx.x;
  const int l = tid & 63, s = l & 15, hi = l >> 4;
  const int w = tid >> 6;
  const int base = blockIdx.x * 16;

  if (tid < 64) {
    c0zr[tid] = bb[tid] + bb[192 + tid];
    c0zr[tid + 64] = bb[tid + 64] + bb[256 + tid];
    bh0a[tid] = bb[128 + tid];
    bh1a[tid] = bb[320 + tid];
    cw0[tid] = Wi[tid]; cw0[tid + 64] = Wi[tid + 64]; cw0[tid + 128] = Wi[tid + 128];
    cw1[tid] = Wi[192 + tid]; cw1[tid + 64] = Wi[256 + tid]; cw1[tid + 128] = Wi[320 + tid];
  }
  for (int k = tid; k < 1536; k += 256) ((uint*)bsp[0])[k] = 0u;  // h(-1)=0

  // ---- gumbel prologue: thread tid = step t, its 16 samples ----
  {
    uint32_t kt0, kt1;
    tf2x32(0u, 1234u, 0u, (uint32_t)tid, kt0, kt1);
    for (int k = 0; k < 16; ++k) {
      const int bidx = base + k;
      const float g0 = gumb_from_bits(rbits32(kt0, kt1, (uint32_t)(2 * bidx)));
      const float g1 = gumb_from_bits(rbits32(kt0, kt1, (uint32_t)(2 * bidx + 1)));
      gl[tid * 16 + k] = make_float2(g0, g1);
    }
  }
  __syncthreads();

  // ---- A fragments: unit tiles {w,4+w,8+w} + logits tile 12, 3 splits ----
  v8s A0[3][2], A1[3][2], A2[3][2];
#pragma unroll
  for (int i3 = 0; i3 < 3; ++i3) {
    const int tile = w + 4 * i3;
#pragma unroll
    for (int kc = 0; kc < 2; ++kc) {
      const int off = (16 * tile + s) * 64 + 32 * kc + 8 * hi;
      A0[i3][kc] = *reinterpret_cast<const v8s*>(w0p + off);
      A1[i3][kc] = *reinterpret_cast<const v8s*>(w1p + off);
      A2[i3][kc] = *reinterpret_cast<const v8s*>(w2p + off);
    }
  }
  v8s L0[2], L1[2], L2[2];
#pragma unroll
  for (int kc = 0; kc < 2; ++kc) {
    const int off = (192 + s) * 64 + 32 * kc + 8 * hi;   // tile 12
    L0[kc] = *reinterpret_cast<const v8s*>(w0p + off);
    L1[kc] = *reinterpret_cast<const v8s*>(w1p + off);
    L2[kc] = *reinterpret_cast<const v8s*>(w2p + off);
  }

  const float bd0 = bd[0], bd1 = bd[1];
  const int u0i = 16 * w + 4 * hi;        // this wave's gate-unit group
  const float4 czv  = *reinterpret_cast<const float4*>(&c0zr[u0i]);
  const float4 crv  = *reinterpret_cast<const float4*>(&c0zr[64 + u0i]);
  const float4 bh0v = *reinterpret_cast<const float4*>(&bh0a[u0i]);
  const float4 bh1v = *reinterpret_cast<const float4*>(&bh1a[u0i]);
  const float4 wz0  = *reinterpret_cast<const float4*>(&cw0[u0i]);
  const float4 wz1  = *reinterpret_cast<const float4*>(&cw1[u0i]);
  const float4 wr0  = *reinterpret_cast<const float4*>(&cw0[64 + u0i]);
  const float4 wr1  = *reinterpret_cast<const float4*>(&cw1[64 + u0i]);
  const float4 wh0  = *reinterpret_cast<const float4*>(&cw0[128 + u0i]);
  const float4 wh1  = *reinterpret_cast<const float4*>(&cw1[128 + u0i]);

  const int kcw = w >> 1;
  const int hgw = (2 * w + (hi >> 1)) & 3;
  const int i0  = (hi & 1) * 4;

  float hreg[4] = {0.0f, 0.0f, 0.0f, 0.0f};
  float lp = 0.0f;
  int p = 0;

  for (int t = 0; t <= NSITES; ++t) {
    // ---- hoisted gumbel read (independent LDS op, hides under B-reads) --
    float2 gc = make_float2(0.0f, 0.0f);
    if (t > 0) gc = gl[(t - 1) * 16 + s];

    // ---- B fragments of h(t-1) from LDS ----
    const ushort* rb = bsp[p] + hi * 128 + s * 8;
    v8s B0[2], B1[2], B2[2];
#pragma unroll
    for (int kc = 0; kc < 2; ++kc) {
      B0[kc] = *reinterpret_cast<const v8s*>(rb + kc * 512);
      B1[kc] = *reinterpret_cast<const v8s*>(rb + 1024 + kc * 512);
      B2[kc] = *reinterpret_cast<const v8s*>(rb + 2048 + kc * 512);
    }

    // ---- logits tile (6 products, low -> high) ----
    v4f al = {0.0f, 0.0f, 0.0f, 0.0f};
#pragma unroll
    for (int kc = 0; kc < 2; ++kc) al = MF(L1[kc], B1[kc], al);
#pragma unroll
    for (int kc = 0; kc < 2; ++kc) al = MF(L2[kc], B0[kc], al);
#pragma unroll
    for (int kc = 0; kc < 2; ++kc) al = MF(L0[kc], B2[kc], al);
#pragma unroll
    for (int kc = 0; kc < 2; ++kc) al = MF(L1[kc], B0[kc], al);
#pragma unroll
    for (int kc = 0; kc < 2; ++kc) al = MF(L0[kc], B1[kc], al);
#pragma unroll
    for (int kc = 0; kc < 2; ++kc) al = MF(L0[kc], B0[kc], al);

    // ---- unit tiles (independent of decision; keep MFMA pipe fed) ----
    v4f acc[3];
    if (t < NSITES) {
#pragma unroll
      for (int i3 = 0; i3 < 3; ++i3) {
        v4f a = {0.0f, 0.0f, 0.0f, 0.0f};
#pragma unroll
        for (int kc = 0; kc < 2; ++kc) a = MF(A2[i3][kc], B0[kc], a);
#pragma unroll
        for (int kc = 0; kc < 2; ++kc) a = MF(A0[i3][kc], B2[kc], a);
#pragma unroll
        for (int kc = 0; kc < 2; ++kc) a = MF(A1[i3][kc], B1[kc], a);
#pragma unroll
        for (int kc = 0; kc < 2; ++kc) a = MF(A1[i3][kc], B0[kc], a);
#pragma unroll
        for (int kc = 0; kc < 2; ++kc) a = MF(A0[i3][kc], B1[kc], a);
#pragma unroll
        for (int kc = 0; kc < 2; ++kc) a = MF(A0[i3][kc], B0[kc], a);
        acc[i3] = a;
      }
    }

    // ---- EARLY decision compare: no exp/log on the gates' path ----
    int scd = 0;
    float l0 = 0.0f, l1 = 0.0f;
    if (t > 0) {
      l0 = al[0] + bd0;
      l1 = al[1] + bd1;
      scd = ((l1 + gc.y) > (l0 + gc.x)) ? 1 : 0;
    }

    if (t < NSITES) {
      // ---- gates for this wave's 16 units (identical math) ----
      float selz[4], selr[4], selh[4];
      if (t == 0) {
#pragma unroll
        for (int r = 0; r < 4; ++r) { selz[r] = 0.0f; selr[r] = 0.0f; selh[r] = 0.0f; }
      } else {
#pragma unroll
        for (int r = 0; r < 4; ++r) {
          selz[r] = scd ? F4(wz1, r) : F4(wz0, r);
          selr[r] = scd ? F4(wr1, r) : F4(wr0, r);
          selh[r] = scd ? F4(wh1, r) : F4(wh0, r);
        }
      }

      uint sp0[4], sp1[4], sp2[4];
#pragma unroll
      for (int r = 0; r < 4; ++r) {
        const float zin = acc[0][r] + F4(czv, r) + selz[r];
        const float rin = acc[1][r] + F4(crv, r) + selr[r];
        const float rhv = acc[2][r] + F4(bh1v, r);
        const float xhv = F4(bh0v, r) + selh[r];
        const float zg = sigmoid_xla(zin);
        const float rg = sigmoid_xla(rin);
        const float hg = tanhf(xhv + rg * rhv);
        const float hn = zg * hreg[r] + (1.0f - zg) * hg;
        hreg[r] = hn;
        const uint u0 = __float_as_uint(hn) & 0xffff0000u;
        const float f0 = __uint_as_float(u0);
        const float r1f = hn - f0;
        const uint u1 = __float_as_uint(r1f) & 0xffff0000u;
        const float f1 = __uint_as_float(u1);
        const float r2f = r1f - f1;
        const uint u2 = __float_as_uint(r2f) & 0xffff0000u;
        sp0[r] = u0 >> 16; sp1[r] = u1 >> 16; sp2[r] = u2 >> 16;
      }
      ushort* wb = bsp[p ^ 1] + kcw * 512 + hgw * 128 + s * 8 + i0;
      {
        uint2 q;
        q.x = sp0[0] | (sp0[1] << 16); q.y = sp0[2] | (sp0[3] << 16);
        *reinterpret_cast<uint2*>(wb) = q;
        q.x = sp1[0] | (sp1[1] << 16); q.y = sp1[2] | (sp1[3] << 16);
        *reinterpret_cast<uint2*>(wb + 1024) = q;
        q.x = sp2[0] | (sp2[1] << 16); q.y = sp2[2] | (sp2[3] << 16);
        *reinterpret_cast<uint2*>(wb + 2048) = q;
      }
    }

    // ---- DEFERRED scoring: exp/log chain overlaps barrier + next reads --
    if (t > 0) {
      const float mmax = fmaxf(l0, l1);
      const float sh0 = l0 - mmax, sh1 = l1 - mmax;
      const float lse = logf(expf(sh0) + expf(sh1));
      lp += (scd ? sh1 : sh0) - lse;
      if (tid < 16) out_s[(size_t)(base + s) * NSITES + (t - 1)] = (float)scd;
    }

    __syncthreads();   // h(t) splits visible; reads of bsp[p] complete
    p ^= 1;
  }

  if (tid < 16) out_lp[base + s] = 0.5f * lp;
}

// ---------------- fallback (ws too small): proven bit-exact path ----------
__global__ __launch_bounds__(64)
void rnn_plain(const float* __restrict__ Wi, const float* __restrict__ Wh,
               const float* __restrict__ bb, const float* __restrict__ Wd,
               const float* __restrict__ bd,
               float* __restrict__ out_s, float* __restrict__ out_lp) {
  const int lane = threadIdx.x;
  const int b = blockIdx.x;

  float wz[NHID], wr[NHID], wh[NHID];
#pragma unroll
  for (int j = 0; j < NHID; ++j) {
    wz[j] = Wh[j * 192 + lane];
    wr[j] = Wh[j * 192 + 64 + lane];
    wh[j] = Wh[j * 192 + 128 + lane];
  }
  const float b1z = bb[192 + lane];
  const float b1r = bb[192 + 64 + lane];
  const float b1h = bb[192 + 128 + lane];
  const float m0z = bb[lane], m0r = bb[64 + lane], m0h = bb[128 + lane];
  const float m1z = Wi[lane] + m0z, m1r = Wi[64 + lane] + m0r, m1h = Wi[128 + lane] + m0h;
  const float m2z = Wi[192 + lane] + m0z, m2r = Wi[192 + 64 + lane] + m0r,
              m2h = Wi[192 + 128 + lane] + m0h;
  const float wd0 = Wd[lane * 2 + 0], wd1 = Wd[lane * 2 + 1];
  const float bd0 = bd[0], bd1 = bd[1];

  float h = 0.0f, lpsum = 0.0f;
  float xz = m0z, xr = m0r, xh = m0h;

  for (int t = 0; t < NSITES; ++t) {
    uint32_t kt0, kt1;
    tf2x32(0u, 1234u, 0u, (uint32_t)t, kt0, kt1);
    const float g0 = gumb_from_bits(rbits32(kt0, kt1, (uint32_t)(2 * b)));
    const float g1 = gumb_from_bits(rbits32(kt0, kt1, (uint32_t)(2 * b + 1)));

    float az = 0.0f, ar = 0.0f, ah = 0.0f;
#pragma unroll
    for (int j = 0; j < NHID; ++j) {
      const float hj = __int_as_float(__builtin_amdgcn_readlane(__float_as_int(h), j));
      az = fmaf(hj, wz[j], az);
      ar = fmaf(hj, wr[j], ar);
      ah = fmaf(hj, wh[j], ah);
    }
    const float rz = az + b1z, rr = ar + b1r, rh = ah + b1h;
    const float zg = sigmoid_xla(xz + rz);
    const float rg = sigmoid_xla(xr + rr);
    const float hg = tanhf(xh + rg * rh);
    h = zg * h + (1.0f - zg) * hg;

    float p0 = h * wd0, p1 = h * wd1;
#pragma unroll
    for (int off = 32; off > 0; off >>= 1) {
      p0 += __shfl_xor(p0, off, 64);
      p1 += __shfl_xor(p1, off, 64);
    }
    const float l0 = p0 + bd0, l1 = p1 + bd1;
    const float mmax = fmaxf(l0, l1);
    const float sh0 = l0 - mmax, sh1 = l1 - mmax;
    const float lse = logf(expf(sh0) + expf(sh1));
    const int si = ((l1 + g1) > (l0 + g0)) ? 1 : 0;
    lpsum += (si ? sh1 : sh0) - lse;
    if (lane == 0) out_s[(size_t)b * NSITES + t] = (float)si;
    xz = si ? m2z : m1z;
    xr = si ? m2r : m1r;
    xh = si ? m2h : m1h;
  }

  if (lane == 0) out_lp[b] = 0.5f * lpsum;
}

extern "C" void kernel_launch(void* const* d_in, const int* in_sizes, int n_in,
                              void* d_out, int out_size, void* d_ws, size_t ws_size,
                              hipStream_t stream) {
  const float* Wi = (const float*)d_in[1];
  const float* Wh = (const float*)d_in[2];
  const float* bb = (const float*)d_in[3];
  const float* Wd = (const float*)d_in[4];
  const float* bd = (const float*)d_in[5];

  float* out    = (float*)d_out;
  float* out_s  = out;                           // [8192][256]
  float* out_lp = out + (size_t)BATCH * NSITES;  // [8192]

  const size_t wb = (size_t)208 * 64 * sizeof(ushort);   // 26 KiB per split

  if (ws_size >= 3 * wb) {
    ushort* w0 = (ushort*)d_ws;
    ushort* w1 = w0 + 208 * 64;
    ushort* w2 = w1 + 208 * 64;
    split_awt<<<(208 * 64 + 255) / 256, 256, 0, stream>>>(Wh, Wd, w0, w1, w2);
    rnn_mfma10<<<BATCH / 16, 256, 0, stream>>>(Wi, bb, bd, w0, w1, w2, out_s, out_lp);
  } else {
    rnn_plain<<<BATCH, 64, 0, stream>>>(Wi, Wh, bb, Wd, bd, out_s, out_lp);
  }
}